// Round 1
// baseline (593.845 us; speedup 1.0000x reference)
//
#include <hip/hip_runtime.h>

// ---------------- problem constants ----------------
#define NODES 50000
#define F_IN 128
#define F_H1 256
#define F_H2 256
#define F_OUT 64

// ---------------- small helpers ----------------
template <int VEC>
__device__ __forceinline__ void vload(float* dst, const float* p) {
  if constexpr (VEC == 4) {
    *reinterpret_cast<float4*>(dst) = *reinterpret_cast<const float4*>(p);
  } else if constexpr (VEC == 2) {
    *reinterpret_cast<float2*>(dst) = *reinterpret_cast<const float2*>(p);
  } else {
    dst[0] = *p;
  }
}
template <int VEC>
__device__ __forceinline__ void vstore(float* p, const float* src) {
  if constexpr (VEC == 4) {
    *reinterpret_cast<float4*>(p) = *reinterpret_cast<const float4*>(src);
  } else if constexpr (VEC == 2) {
    *reinterpret_cast<float2*>(p) = *reinterpret_cast<const float2*>(src);
  } else {
    *p = src[0];
  }
}

// ---------------- degree / CSR build ----------------
__global__ void k_init(int* deg_out, int* deg_in, int* cursor, int n) {
  int i = blockIdx.x * blockDim.x + threadIdx.x;
  if (i < n) { deg_out[i] = 1; deg_in[i] = 1; cursor[i] = 0; }  // self-loop counts as 1
}

__global__ void k_count(const int* __restrict__ src, const int* __restrict__ dst,
                        int* deg_out, int* deg_in, int e) {
  int i = blockIdx.x * blockDim.x + threadIdx.x;
  if (i < e) {
    atomicAdd(&deg_out[src[i]], 1);
    atomicAdd(&deg_in[dst[i]], 1);
  }
}

__global__ void k_norm(const int* __restrict__ deg_out, const int* __restrict__ deg_in,
                       float* ns, float* nd, int n) {
  int i = blockIdx.x * blockDim.x + threadIdx.x;
  if (i < n) {
    ns[i] = rsqrtf((float)deg_out[i]);
    nd[i] = rsqrtf((float)deg_in[i]);
  }
}

// exclusive prefix over (deg_in - 1): CSR row_ptr (self-loops NOT stored in CSR)
__global__ __launch_bounds__(1024) void k_scan(const int* __restrict__ deg_in,
                                               int* __restrict__ row_ptr, int n) {
  __shared__ int sums[1024];
  const int t = threadIdx.x;
  const int C = (n + 1023) / 1024;
  const int base = t * C;
  int s = 0;
  for (int i = 0; i < C; ++i) {
    int idx = base + i;
    if (idx < n) s += deg_in[idx] - 1;
  }
  sums[t] = s;
  __syncthreads();
  for (int off = 1; off < 1024; off <<= 1) {
    int v = (t >= off) ? sums[t - off] : 0;
    __syncthreads();
    sums[t] += v;
    __syncthreads();
  }
  int run = (t == 0) ? 0 : sums[t - 1];
  for (int i = 0; i < C; ++i) {
    int idx = base + i;
    if (idx < n) { row_ptr[idx] = run; run += deg_in[idx] - 1; }
  }
  if (t == 1023) row_ptr[n] = sums[1023];
}

__global__ void k_scatter(const int* __restrict__ src, const int* __restrict__ dst,
                          const int* __restrict__ row_ptr, int* cursor,
                          int* __restrict__ csr_src, int e) {
  int i = blockIdx.x * blockDim.x + threadIdx.x;
  if (i < e) {
    int d = dst[i];
    int pos = row_ptr[d] + atomicAdd(&cursor[d], 1);
    csr_src[pos] = src[i];
  }
}

// ---------------- SpMM: Y[v] = nd[v] * ( sum_{u->v} w(u)*X[u] + w(v)*X[v] ) (+bias)
// w(u) = ns[u] if USE_NS else 1.  One wave per node; lane owns D/64 floats.
template <int D, bool USE_NS, bool BIAS>
__global__ __launch_bounds__(256) void k_spmm(
    const float* __restrict__ X, const int* __restrict__ row_ptr,
    const int* __restrict__ csr_src, const float* __restrict__ ns,
    const float* __restrict__ nd, const float* __restrict__ bias,
    float* __restrict__ Y, int n) {
  constexpr int VEC = D / 64;
  const int wid = (blockIdx.x * blockDim.x + threadIdx.x) >> 6;
  const int lane = threadIdx.x & 63;
  if (wid >= n) return;
  const int v = wid;
  const int off = lane * VEC;

  float acc[VEC];
  {
    float t[VEC];
    vload<VEC>(t, X + (size_t)v * D + off);
    float w = USE_NS ? ns[v] : 1.0f;
#pragma unroll
    for (int i = 0; i < VEC; ++i) acc[i] = w * t[i];
  }

  const int beg = row_ptr[v];
  const int end = row_ptr[v + 1];
  int e = beg;
#pragma unroll 1
  for (; e + 4 <= end; e += 4) {
    int u0 = csr_src[e + 0], u1 = csr_src[e + 1], u2 = csr_src[e + 2], u3 = csr_src[e + 3];
    float t0[VEC], t1[VEC], t2[VEC], t3[VEC];
    vload<VEC>(t0, X + (size_t)u0 * D + off);
    vload<VEC>(t1, X + (size_t)u1 * D + off);
    vload<VEC>(t2, X + (size_t)u2 * D + off);
    vload<VEC>(t3, X + (size_t)u3 * D + off);
    float w0 = USE_NS ? ns[u0] : 1.0f;
    float w1 = USE_NS ? ns[u1] : 1.0f;
    float w2 = USE_NS ? ns[u2] : 1.0f;
    float w3 = USE_NS ? ns[u3] : 1.0f;
#pragma unroll
    for (int i = 0; i < VEC; ++i)
      acc[i] += w0 * t0[i] + w1 * t1[i] + w2 * t2[i] + w3 * t3[i];
  }
  for (; e < end; ++e) {
    int u = csr_src[e];
    float t[VEC];
    vload<VEC>(t, X + (size_t)u * D + off);
    float w = USE_NS ? ns[u] : 1.0f;
#pragma unroll
    for (int i = 0; i < VEC; ++i) acc[i] += w * t[i];
  }

  const float sc = nd[v];
  float out[VEC];
#pragma unroll
  for (int i = 0; i < VEC; ++i) {
    out[i] = sc * acc[i];
    if (BIAS) out[i] += bias[off + i];
  }
  vstore<VEC>(Y + (size_t)v * D + off, out);
}

// ---------------- f32 GEMM: C = op(A @ W (+bias)), A:[M,K] row-major, W:[K,NOUT]
// tile 64x64x32, 256 threads, 4x4 micro-tile. NSROW scales A rows by ns.
template <int K, int NOUT, bool RELU, bool BIAS, bool NSROW>
__global__ __launch_bounds__(256) void k_gemm(
    const float* __restrict__ A, const float* __restrict__ W,
    const float* __restrict__ bias, const float* __restrict__ ns,
    float* __restrict__ C, int M) {
  constexpr int BM = 64, BN = 64, BK = 32;
  __shared__ float As[BK][BM + 4];  // transposed: As[k][m], pad breaks conflicts
  __shared__ float Bs[BK][BN];
  const int bm = blockIdx.x * BM;
  const int bn = blockIdx.y * BN;
  const int tid = threadIdx.x;
  const int tx = tid & 15;   // col group (x4)
  const int ty = tid >> 4;   // row group (x4)
  float acc[4][4] = {};

  for (int kk = 0; kk < K; kk += BK) {
    // A tile: 64 rows x 32 cols, float4 x2 per thread, store transposed
#pragma unroll
    for (int rep = 0; rep < 2; ++rep) {
      int idx = tid + rep * 256;        // 0..511 float4 slots
      int r = idx >> 3;                 // 0..63
      int c4 = (idx & 7) << 2;          // 0,4,...,28
      int grow = bm + r;
      float4 v = make_float4(0.f, 0.f, 0.f, 0.f);
      if (grow < M) {
        v = *reinterpret_cast<const float4*>(A + (size_t)grow * K + kk + c4);
        if (NSROW) { float s = ns[grow]; v.x *= s; v.y *= s; v.z *= s; v.w *= s; }
      }
      As[c4 + 0][r] = v.x; As[c4 + 1][r] = v.y;
      As[c4 + 2][r] = v.z; As[c4 + 3][r] = v.w;
    }
    // B tile: 32 rows x 64 cols
#pragma unroll
    for (int rep = 0; rep < 2; ++rep) {
      int idx = tid + rep * 256;
      int r = idx >> 4;                 // 0..31
      int c4 = (idx & 15) << 2;         // 0..60
      *reinterpret_cast<float4*>(&Bs[r][c4]) =
          *reinterpret_cast<const float4*>(W + (size_t)(kk + r) * NOUT + bn + c4);
    }
    __syncthreads();
#pragma unroll
    for (int k = 0; k < BK; ++k) {
      float4 a = *reinterpret_cast<const float4*>(&As[k][ty << 2]);
      float4 b = *reinterpret_cast<const float4*>(&Bs[k][tx << 2]);
      acc[0][0] += a.x * b.x; acc[0][1] += a.x * b.y; acc[0][2] += a.x * b.z; acc[0][3] += a.x * b.w;
      acc[1][0] += a.y * b.x; acc[1][1] += a.y * b.y; acc[1][2] += a.y * b.z; acc[1][3] += a.y * b.w;
      acc[2][0] += a.z * b.x; acc[2][1] += a.z * b.y; acc[2][2] += a.z * b.z; acc[2][3] += a.z * b.w;
      acc[3][0] += a.w * b.x; acc[3][1] += a.w * b.y; acc[3][2] += a.w * b.z; acc[3][3] += a.w * b.w;
    }
    __syncthreads();
  }

#pragma unroll
  for (int i = 0; i < 4; ++i) {
    int row = bm + (ty << 2) + i;
    if (row >= M) continue;
    float4 o = make_float4(acc[i][0], acc[i][1], acc[i][2], acc[i][3]);
    if (BIAS) {
      float4 bb = *reinterpret_cast<const float4*>(bias + bn + (tx << 2));
      o.x += bb.x; o.y += bb.y; o.z += bb.z; o.w += bb.w;
    }
    if (RELU) {
      o.x = fmaxf(o.x, 0.f); o.y = fmaxf(o.y, 0.f);
      o.z = fmaxf(o.z, 0.f); o.w = fmaxf(o.w, 0.f);
    }
    *reinterpret_cast<float4*>(C + (size_t)row * NOUT + bn + (tx << 2)) = o;
  }
}

// ---------------- launch ----------------
extern "C" void kernel_launch(void* const* d_in, const int* in_sizes, int n_in,
                              void* d_out, int out_size, void* d_ws, size_t ws_size,
                              hipStream_t stream) {
  const float* feats = (const float*)d_in[0];
  const float* W1 = (const float*)d_in[1];
  const float* b1 = (const float*)d_in[2];
  const float* W2 = (const float*)d_in[3];
  const float* b2 = (const float*)d_in[4];
  const float* W3 = (const float*)d_in[5];
  const float* b3 = (const float*)d_in[6];
  const int* src = (const int*)d_in[7];
  const int* dst = (const int*)d_in[8];
  float* out = (float*)d_out;
  const int N = NODES;
  const int E = in_sizes[7];

  char* ws = (char*)d_ws;
  size_t off = 0;
  auto alloc = [&](size_t bytes) -> void* {
    void* p = ws + off;
    off += (bytes + 255) & ~(size_t)255;
    return p;
  };
  float* bufA = (float*)alloc((size_t)N * 256 * sizeof(float));
  float* bufB = (float*)alloc((size_t)N * 256 * sizeof(float));
  int* deg_out = (int*)alloc((size_t)N * sizeof(int));
  int* deg_in = (int*)alloc((size_t)N * sizeof(int));
  int* cursor = (int*)alloc((size_t)N * sizeof(int));
  float* ns = (float*)alloc((size_t)N * sizeof(float));
  float* nd = (float*)alloc((size_t)N * sizeof(float));
  int* row_ptr = (int*)alloc((size_t)(N + 1) * sizeof(int));
  int* csr_src = (int*)alloc((size_t)E * sizeof(int));
  (void)ws_size; (void)n_in; (void)out_size;

  // ---- graph preprocessing (every call; deterministic work) ----
  hipLaunchKernelGGL(k_init, dim3((N + 255) / 256), dim3(256), 0, stream,
                     deg_out, deg_in, cursor, N);
  hipLaunchKernelGGL(k_count, dim3((E + 255) / 256), dim3(256), 0, stream,
                     src, dst, deg_out, deg_in, E);
  hipLaunchKernelGGL(k_norm, dim3((N + 255) / 256), dim3(256), 0, stream,
                     deg_out, deg_in, ns, nd, N);
  hipLaunchKernelGGL(k_scan, dim3(1), dim3(1024), 0, stream, deg_in, row_ptr, N);
  hipLaunchKernelGGL(k_scatter, dim3((E + 255) / 256), dim3(256), 0, stream,
                     src, dst, row_ptr, cursor, csr_src, E);

  const int spmm_blocks = (N * 64 + 255) / 256;

  // ---- layer 1: SpMM(d=128) then GEMM 128->256 (+b1, relu) ----
  hipLaunchKernelGGL((k_spmm<128, true, false>), dim3(spmm_blocks), dim3(256), 0, stream,
                     feats, row_ptr, csr_src, ns, nd, nullptr, bufA, N);
  hipLaunchKernelGGL((k_gemm<128, 256, true, true, false>),
                     dim3((N + 63) / 64, 256 / 64), dim3(256), 0, stream,
                     bufA, W1, b1, nullptr, bufB, N);

  // ---- layer 2: SpMM(d=256) then GEMM 256->256 (+b2, relu) ----
  hipLaunchKernelGGL((k_spmm<256, true, false>), dim3(spmm_blocks), dim3(256), 0, stream,
                     bufB, row_ptr, csr_src, ns, nd, nullptr, bufA, N);
  hipLaunchKernelGGL((k_gemm<256, 256, true, true, false>),
                     dim3((N + 63) / 64, 256 / 64), dim3(256), 0, stream,
                     bufA, W2, b2, nullptr, bufB, N);

  // ---- layer 3: GEMM (ns-scaled rows) 256->64 first, then SpMM(d=64) +b3 ----
  hipLaunchKernelGGL((k_gemm<256, 64, false, false, true>),
                     dim3((N + 63) / 64, 1), dim3(256), 0, stream,
                     bufB, W3, nullptr, ns, bufA, N);
  hipLaunchKernelGGL((k_spmm<64, false, true>), dim3(spmm_blocks), dim3(256), 0, stream,
                     bufA, row_ptr, csr_src, nullptr, nd, b3, out, N);
}

// Round 2
// 529.031 us; speedup vs baseline: 1.1225x; 1.1225x over previous
//
#include <hip/hip_runtime.h>
#include <stdint.h>

// ---------------- problem constants ----------------
#define NODES 50000
#define F_IN 128
#define F_H1 256
#define F_H2 256
#define F_OUT 64

using f32x4   = __attribute__((ext_vector_type(4))) float;
using bf16x8  = __attribute__((ext_vector_type(8))) short;     // 8 bf16 in 4 VGPRs
using ushort4v = __attribute__((ext_vector_type(4))) unsigned short;
using ushort8v = __attribute__((ext_vector_type(8))) unsigned short;

// ---------------- bf16 split helpers ----------------
__device__ __forceinline__ unsigned short f2bf(float f) {
  union { float f; uint32_t u; } v; v.f = f;
  uint32_t r = v.u + 0x7FFFu + ((v.u >> 16) & 1u);   // round-to-nearest-even
  return (unsigned short)(r >> 16);
}
__device__ __forceinline__ float bf2f(unsigned short h) {
  union { uint32_t u; float f; } v; v.u = (uint32_t)h << 16;
  return v.f;
}

// ---------------- small helpers ----------------
template <int VEC>
__device__ __forceinline__ void vload(float* dst, const float* p) {
  if constexpr (VEC == 4) {
    *reinterpret_cast<float4*>(dst) = *reinterpret_cast<const float4*>(p);
  } else if constexpr (VEC == 2) {
    *reinterpret_cast<float2*>(dst) = *reinterpret_cast<const float2*>(p);
  } else {
    dst[0] = *p;
  }
}
template <int VEC>
__device__ __forceinline__ void vstore(float* p, const float* src) {
  if constexpr (VEC == 4) {
    *reinterpret_cast<float4*>(p) = *reinterpret_cast<const float4*>(src);
  } else if constexpr (VEC == 2) {
    *reinterpret_cast<float2*>(p) = *reinterpret_cast<const float2*>(src);
  } else {
    *p = src[0];
  }
}

// ---------------- degree / CSR build ----------------
__global__ void k_init(int* deg_out, int* deg_in, int* cursor, int n) {
  int i = blockIdx.x * blockDim.x + threadIdx.x;
  if (i < n) { deg_out[i] = 1; deg_in[i] = 1; cursor[i] = 0; }  // self-loop counts as 1
}

__global__ void k_count(const int* __restrict__ src, const int* __restrict__ dst,
                        int* deg_out, int* deg_in, int e) {
  int i = blockIdx.x * blockDim.x + threadIdx.x;
  if (i < e) {
    atomicAdd(&deg_out[src[i]], 1);
    atomicAdd(&deg_in[dst[i]], 1);
  }
}

__global__ void k_norm(const int* __restrict__ deg_out, const int* __restrict__ deg_in,
                       float* ns, float* nd, int n) {
  int i = blockIdx.x * blockDim.x + threadIdx.x;
  if (i < n) {
    ns[i] = rsqrtf((float)deg_out[i]);
    nd[i] = rsqrtf((float)deg_in[i]);
  }
}

// exclusive prefix over (deg_in - 1): CSR row_ptr (self-loops NOT stored in CSR)
__global__ __launch_bounds__(1024) void k_scan(const int* __restrict__ deg_in,
                                               int* __restrict__ row_ptr, int n) {
  __shared__ int sums[1024];
  const int t = threadIdx.x;
  const int C = (n + 1023) / 1024;
  const int base = t * C;
  int s = 0;
  for (int i = 0; i < C; ++i) {
    int idx = base + i;
    if (idx < n) s += deg_in[idx] - 1;
  }
  sums[t] = s;
  __syncthreads();
  for (int off = 1; off < 1024; off <<= 1) {
    int v = (t >= off) ? sums[t - off] : 0;
    __syncthreads();
    sums[t] += v;
    __syncthreads();
  }
  int run = (t == 0) ? 0 : sums[t - 1];
  for (int i = 0; i < C; ++i) {
    int idx = base + i;
    if (idx < n) { row_ptr[idx] = run; run += deg_in[idx] - 1; }
  }
  if (t == 1023) row_ptr[n] = sums[1023];
}

__global__ void k_scatter(const int* __restrict__ src, const int* __restrict__ dst,
                          const int* __restrict__ row_ptr, int* cursor,
                          int* __restrict__ csr_src, int e) {
  int i = blockIdx.x * blockDim.x + threadIdx.x;
  if (i < e) {
    int d = dst[i];
    int pos = row_ptr[d] + atomicAdd(&cursor[d], 1);
    csr_src[pos] = src[i];
  }
}

// ---------------- weight prep: W[K][NOUT] f32 -> Wt_hi/Wt_lo [NOUT][K] bf16 ----
__global__ void k_wprep(const float* __restrict__ W, unsigned short* __restrict__ Wt_hi,
                        unsigned short* __restrict__ Wt_lo, int K, int NOUT) {
  int i = blockIdx.x * blockDim.x + threadIdx.x;
  if (i < K * NOUT) {
    int k = i / NOUT, n = i % NOUT;
    float w = W[i];
    unsigned short h = f2bf(w);
    unsigned short l = f2bf(w - bf2f(h));
    Wt_hi[(size_t)n * K + k] = h;
    Wt_lo[(size_t)n * K + k] = l;
  }
}

// ---------------- SpMM: Y[v] = nd[v] * ( sum_{u->v} w(u)*X[u] + w(v)*X[v] ) (+bias)
template <int D, bool USE_NS, bool BIAS>
__global__ __launch_bounds__(256) void k_spmm(
    const float* __restrict__ X, const int* __restrict__ row_ptr,
    const int* __restrict__ csr_src, const float* __restrict__ ns,
    const float* __restrict__ nd, const float* __restrict__ bias,
    float* __restrict__ Y, int n) {
  constexpr int VEC = D / 64;
  const int wid = (blockIdx.x * blockDim.x + threadIdx.x) >> 6;
  const int lane = threadIdx.x & 63;
  if (wid >= n) return;
  const int v = wid;
  const int off = lane * VEC;

  float acc[VEC];
  {
    float t[VEC];
    vload<VEC>(t, X + (size_t)v * D + off);
    float w = USE_NS ? ns[v] : 1.0f;
#pragma unroll
    for (int i = 0; i < VEC; ++i) acc[i] = w * t[i];
  }

  const int beg = row_ptr[v];
  const int end = row_ptr[v + 1];
  int e = beg;
#pragma unroll 1
  for (; e + 4 <= end; e += 4) {
    int u0 = csr_src[e + 0], u1 = csr_src[e + 1], u2 = csr_src[e + 2], u3 = csr_src[e + 3];
    float t0[VEC], t1[VEC], t2[VEC], t3[VEC];
    vload<VEC>(t0, X + (size_t)u0 * D + off);
    vload<VEC>(t1, X + (size_t)u1 * D + off);
    vload<VEC>(t2, X + (size_t)u2 * D + off);
    vload<VEC>(t3, X + (size_t)u3 * D + off);
    float w0 = USE_NS ? ns[u0] : 1.0f;
    float w1 = USE_NS ? ns[u1] : 1.0f;
    float w2 = USE_NS ? ns[u2] : 1.0f;
    float w3 = USE_NS ? ns[u3] : 1.0f;
#pragma unroll
    for (int i = 0; i < VEC; ++i)
      acc[i] += w0 * t0[i] + w1 * t1[i] + w2 * t2[i] + w3 * t3[i];
  }
  for (; e < end; ++e) {
    int u = csr_src[e];
    float t[VEC];
    vload<VEC>(t, X + (size_t)u * D + off);
    float w = USE_NS ? ns[u] : 1.0f;
#pragma unroll
    for (int i = 0; i < VEC; ++i) acc[i] += w * t[i];
  }

  const float sc = nd[v];
  float out[VEC];
#pragma unroll
  for (int i = 0; i < VEC; ++i) {
    out[i] = sc * acc[i];
    if (BIAS) out[i] += bias[off + i];
  }
  vstore<VEC>(Y + (size_t)v * D + off, out);
}

// ---------------- split-bf16 MFMA GEMM ----------------
// C[M][NOUT] = op( A[M][K] @ W[K][NOUT] (+bias) ), via A_hi*W_hi + A_hi*W_lo + A_lo*W_hi
// with mfma_f32_16x16x32_bf16.  W pre-split & pre-transposed: Wt[n][k] bf16.
// Block: 256 threads = 4 waves arranged WM x WN; tile BM x BN (BN == NOUT, A read once).
// A-frag: row = lane&15, k = (lane>>4)*8 + j (contiguous 8 bf16 -> ds_read_b128)
// B-frag: col = lane&15, k = (lane>>4)*8 + j
// C/D:    col = lane&15, row = (lane>>4)*4 + reg   [verified layout, learn_hip m89/m91]
template <int K, int NOUT, int BM, int WM, int WN, int MF, int NF,
          bool RELU, bool BIAS, bool NSROW>
__global__ __launch_bounds__(256) void k_gemm_mfma(
    const float* __restrict__ A,
    const unsigned short* __restrict__ Wt_hi, const unsigned short* __restrict__ Wt_lo,
    const float* __restrict__ bias, const float* __restrict__ ns,
    float* __restrict__ C, int M) {
  constexpr int BN = WN * NF * 16;
  static_assert(BM == WM * MF * 16, "BM mismatch");
  static_assert(BN == NOUT, "BN must equal NOUT");
  constexpr int LDP = 40;  // row pad: 80B stride -> bank stride 20 -> <=2-way (free), 16B aligned

  __shared__ unsigned short As[2][BM][LDP];   // [hi/lo][row][k]
  __shared__ unsigned short Ws[2][BN][LDP];   // [hi/lo][col][k]

  const int tid = threadIdx.x;
  const int bm = blockIdx.x * BM;
  const int lane = tid & 63;
  const int wave = tid >> 6;
  const int wmi = wave / WN;
  const int wni = wave % WN;
  const int rl = lane & 15;
  const int kg = lane >> 4;       // 0..3
  const int kb = kg * 8;

  f32x4 acc[MF][NF];
#pragma unroll
  for (int m = 0; m < MF; ++m)
#pragma unroll
    for (int n = 0; n < NF; ++n) acc[m][n] = (f32x4){0.f, 0.f, 0.f, 0.f};

  for (int kk = 0; kk < K; kk += 32) {
    // ---- stage A tile (BM x 32 f32), split into hi/lo bf16 ----
#pragma unroll
    for (int s0 = 0; s0 < BM * 8; s0 += 256) {
      int s = s0 + tid;
      int r = s >> 3, c4 = (s & 7) << 2;
      int grow = bm + r;
      float4 v = make_float4(0.f, 0.f, 0.f, 0.f);
      if (grow < M) {
        v = *reinterpret_cast<const float4*>(A + (size_t)grow * K + kk + c4);
        if (NSROW) { float sc = ns[grow]; v.x *= sc; v.y *= sc; v.z *= sc; v.w *= sc; }
      }
      ushort4v hi, lo;
      hi[0] = f2bf(v.x); lo[0] = f2bf(v.x - bf2f(hi[0]));
      hi[1] = f2bf(v.y); lo[1] = f2bf(v.y - bf2f(hi[1]));
      hi[2] = f2bf(v.z); lo[2] = f2bf(v.z - bf2f(hi[2]));
      hi[3] = f2bf(v.w); lo[3] = f2bf(v.w - bf2f(hi[3]));
      *reinterpret_cast<ushort4v*>(&As[0][r][c4]) = hi;
      *reinterpret_cast<ushort4v*>(&As[1][r][c4]) = lo;
    }
    // ---- stage W tile (BN cols x 32 k), already bf16, transposed in global ----
#pragma unroll
    for (int s0 = 0; s0 < BN * 4; s0 += 256) {
      int s = s0 + tid;
      int n = s >> 2, k8 = (s & 3) << 3;
      *reinterpret_cast<ushort8v*>(&Ws[0][n][k8]) =
          *reinterpret_cast<const ushort8v*>(Wt_hi + (size_t)n * K + kk + k8);
      *reinterpret_cast<ushort8v*>(&Ws[1][n][k8]) =
          *reinterpret_cast<const ushort8v*>(Wt_lo + (size_t)n * K + kk + k8);
    }
    __syncthreads();

    bf16x8 af[2][MF], bfr[2][NF];
#pragma unroll
    for (int m = 0; m < MF; ++m) {
      const int r = wmi * MF * 16 + m * 16 + rl;
      af[0][m] = *reinterpret_cast<const bf16x8*>(&As[0][r][kb]);
      af[1][m] = *reinterpret_cast<const bf16x8*>(&As[1][r][kb]);
    }
#pragma unroll
    for (int n = 0; n < NF; ++n) {
      const int c = wni * NF * 16 + n * 16 + rl;
      bfr[0][n] = *reinterpret_cast<const bf16x8*>(&Ws[0][c][kb]);
      bfr[1][n] = *reinterpret_cast<const bf16x8*>(&Ws[1][c][kb]);
    }
#pragma unroll
    for (int m = 0; m < MF; ++m)
#pragma unroll
      for (int n = 0; n < NF; ++n) {
        acc[m][n] = __builtin_amdgcn_mfma_f32_16x16x32_bf16(af[0][m], bfr[0][n], acc[m][n], 0, 0, 0);
        acc[m][n] = __builtin_amdgcn_mfma_f32_16x16x32_bf16(af[0][m], bfr[1][n], acc[m][n], 0, 0, 0);
        acc[m][n] = __builtin_amdgcn_mfma_f32_16x16x32_bf16(af[1][m], bfr[0][n], acc[m][n], 0, 0, 0);
      }
    __syncthreads();
  }

  // ---- epilogue ----
#pragma unroll
  for (int m = 0; m < MF; ++m) {
#pragma unroll
    for (int n = 0; n < NF; ++n) {
      const int col = wni * NF * 16 + n * 16 + rl;
      const float bb = BIAS ? bias[col] : 0.f;
      const int rowbase = bm + wmi * MF * 16 + m * 16 + kg * 4;
#pragma unroll
      for (int i = 0; i < 4; ++i) {
        int grow = rowbase + i;
        if (grow < M) {
          float val = acc[m][n][i] + bb;
          if (RELU) val = fmaxf(val, 0.f);
          C[(size_t)grow * NOUT + col] = val;
        }
      }
    }
  }
}

// ---------------- launch ----------------
extern "C" void kernel_launch(void* const* d_in, const int* in_sizes, int n_in,
                              void* d_out, int out_size, void* d_ws, size_t ws_size,
                              hipStream_t stream) {
  const float* feats = (const float*)d_in[0];
  const float* W1 = (const float*)d_in[1];
  const float* b1 = (const float*)d_in[2];
  const float* W2 = (const float*)d_in[3];
  const float* b2 = (const float*)d_in[4];
  const float* W3 = (const float*)d_in[5];
  const float* b3 = (const float*)d_in[6];
  const int* src = (const int*)d_in[7];
  const int* dst = (const int*)d_in[8];
  float* out = (float*)d_out;
  const int N = NODES;
  const int E = in_sizes[7];

  char* ws = (char*)d_ws;
  size_t off = 0;
  auto alloc = [&](size_t bytes) -> void* {
    void* p = ws + off;
    off += (bytes + 255) & ~(size_t)255;
    return p;
  };
  float* bufA = (float*)alloc((size_t)N * 256 * sizeof(float));
  float* bufB = (float*)alloc((size_t)N * 256 * sizeof(float));
  int* deg_out = (int*)alloc((size_t)N * sizeof(int));
  int* deg_in = (int*)alloc((size_t)N * sizeof(int));
  int* cursor = (int*)alloc((size_t)N * sizeof(int));
  float* ns = (float*)alloc((size_t)N * sizeof(float));
  float* nd = (float*)alloc((size_t)N * sizeof(float));
  int* row_ptr = (int*)alloc((size_t)(N + 1) * sizeof(int));
  int* csr_src = (int*)alloc((size_t)E * sizeof(int));
  unsigned short* w1hi = (unsigned short*)alloc((size_t)F_IN * F_H1 * 2);
  unsigned short* w1lo = (unsigned short*)alloc((size_t)F_IN * F_H1 * 2);
  unsigned short* w2hi = (unsigned short*)alloc((size_t)F_H1 * F_H2 * 2);
  unsigned short* w2lo = (unsigned short*)alloc((size_t)F_H1 * F_H2 * 2);
  unsigned short* w3hi = (unsigned short*)alloc((size_t)F_H2 * F_OUT * 2);
  unsigned short* w3lo = (unsigned short*)alloc((size_t)F_H2 * F_OUT * 2);
  (void)ws_size; (void)n_in; (void)out_size;

  // ---- weight split/transpose (tiny) ----
  hipLaunchKernelGGL(k_wprep, dim3((F_IN * F_H1 + 255) / 256), dim3(256), 0, stream,
                     W1, w1hi, w1lo, F_IN, F_H1);
  hipLaunchKernelGGL(k_wprep, dim3((F_H1 * F_H2 + 255) / 256), dim3(256), 0, stream,
                     W2, w2hi, w2lo, F_H1, F_H2);
  hipLaunchKernelGGL(k_wprep, dim3((F_H2 * F_OUT + 255) / 256), dim3(256), 0, stream,
                     W3, w3hi, w3lo, F_H2, F_OUT);

  // ---- graph preprocessing (every call; deterministic work) ----
  hipLaunchKernelGGL(k_init, dim3((N + 255) / 256), dim3(256), 0, stream,
                     deg_out, deg_in, cursor, N);
  hipLaunchKernelGGL(k_count, dim3((E + 255) / 256), dim3(256), 0, stream,
                     src, dst, deg_out, deg_in, E);
  hipLaunchKernelGGL(k_norm, dim3((N + 255) / 256), dim3(256), 0, stream,
                     deg_out, deg_in, ns, nd, N);
  hipLaunchKernelGGL(k_scan, dim3(1), dim3(1024), 0, stream, deg_in, row_ptr, N);
  hipLaunchKernelGGL(k_scatter, dim3((E + 255) / 256), dim3(256), 0, stream,
                     src, dst, row_ptr, cursor, csr_src, E);

  const int spmm_blocks = (N * 64 + 255) / 256;

  // ---- layer 1: SpMM(d=128) then MFMA-GEMM 128->256 (+b1, relu) ----
  hipLaunchKernelGGL((k_spmm<128, true, false>), dim3(spmm_blocks), dim3(256), 0, stream,
                     feats, row_ptr, csr_src, ns, nd, nullptr, bufA, N);
  hipLaunchKernelGGL((k_gemm_mfma<128, 256, 64, 1, 4, 4, 4, true, true, false>),
                     dim3((N + 63) / 64), dim3(256), 0, stream,
                     bufA, w1hi, w1lo, b1, nullptr, bufB, N);

  // ---- layer 2: SpMM(d=256) then MFMA-GEMM 256->256 (+b2, relu) ----
  hipLaunchKernelGGL((k_spmm<256, true, false>), dim3(spmm_blocks), dim3(256), 0, stream,
                     bufB, row_ptr, csr_src, ns, nd, nullptr, bufA, N);
  hipLaunchKernelGGL((k_gemm_mfma<256, 256, 64, 1, 4, 4, 4, true, true, false>),
                     dim3((N + 63) / 64), dim3(256), 0, stream,
                     bufA, w2hi, w2lo, b2, nullptr, bufB, N);

  // ---- layer 3: MFMA-GEMM (ns-scaled rows) 256->64 first, then SpMM(d=64) +b3 ----
  hipLaunchKernelGGL((k_gemm_mfma<256, 64, 128, 4, 1, 2, 4, false, false, true>),
                     dim3((N + 127) / 128), dim3(256), 0, stream,
                     bufB, w3hi, w3lo, nullptr, ns, bufA, N);
  hipLaunchKernelGGL((k_spmm<64, false, true>), dim3(spmm_blocks), dim3(256), 0, stream,
                     bufA, row_ptr, csr_src, nullptr, nd, b3, out, N);
}